// Round 3
// baseline (189.046 us; speedup 1.0000x reference)
//
#include <hip/hip_runtime.h>
#include <stdint.h>

#define NTOK 1536
#define CDIM 768
#define NH 8
#define DKH 64
#define DVH 96
#define NF 96

typedef unsigned short u16;
typedef __attribute__((ext_vector_type(8))) short s16x8;   // 8 bf16 (4 VGPRs)
typedef __attribute__((ext_vector_type(4))) float f32x4;   // MFMA acc

__device__ __forceinline__ float b2f(u16 u) {
    union { uint32_t i; float f; } v; v.i = ((uint32_t)u) << 16; return v.f;
}
__device__ __forceinline__ u16 f2b(float f) {
    union { float f; uint32_t i; } v; v.f = f;
    uint32_t x = v.i;
    return (u16)((x + 0x7FFFu + ((x >> 16) & 1u)) >> 16);
}
__device__ __forceinline__ float ldin(const void* p, int i, int f32) {
    return f32 ? ((const float*)p)[i] : b2f(((const u16*)p)[i]);
}

// Inline wave-uniform dtype probe: scans first 256 u16 words.  A true-bf16
// buffer never decodes |v|>=1e6; fp32 mantissa-low words do w.p. ~0.42 each
// (~128 of the 256 samples) -> miss prob ~3e-29.  Returns 1 iff fp32.
__device__ __forceinline__ int probe_f32(const void* p) {
    const u16* a = (const u16*)p;
    int lane = threadIdx.x & 63;
    int bad = 0;
#pragma unroll
    for (int t = 0; t < 4; ++t) {
        float v = b2f(a[lane + t * 64]);
        if (!(fabsf(v) < 1e6f)) bad = 1;
    }
    return __ballot(bad) != 0ull;
}

// Fragment-major: element (m, kk) of a (16 x 32k) 512-elem block sits at
// ((kk>>3)*16 + m)*8 + (kk&7)  == lane*8 + slot.
#define FIDX(m, kk) ((((kk) >> 3) * 16 + (m)) * 8 + ((kk) & 7))

// ---------------------------------------------------------------------------
// ws layout (float offsets).
// ---------------------------------------------------------------------------
#define OFF_S11  16
#define OFF_QF   (OFF_S11 + 147456)     // u16: qfrag  (h,ti:96,kc2:2)  A-frags
#define OFF_KF   (OFF_QF + 393216)      // u16: kfrag  (h,tj:96,kc2:2)  B-frags
#define OFF_VF   (OFF_KF + 393216)      // u16: vfrag  (h,jc:48,nt:6)   B-frags
#define OFF_AOF  (OFF_VF + 589824)      // u16: aofrag (ti:96,kc:24)    A-frags

// ---------------------------------------------------------------------------
// A-frag self-staging (contiguous 16B/lane): lane holds row (lane&15),
// cols kc*32 + (lane>>4)*8 .. +8.
// ---------------------------------------------------------------------------
__device__ __forceinline__ s16x8 ldfragA(const void* x, int f32, int row16,
                                         int kc, int lane) {
    int m = lane & 15, kq = lane >> 4;
    int src = (row16 * 16 + m) * CDIM + kc * 32 + kq * 8;
    union { u16 uu[8]; uint4 v; s16x8 s; } pk;
    if (f32) {
        const float* xp = (const float*)x + src;
        float4 a0 = *(const float4*)(xp);
        float4 a1 = *(const float4*)(xp + 4);
        pk.uu[0] = f2b(a0.x); pk.uu[1] = f2b(a0.y);
        pk.uu[2] = f2b(a0.z); pk.uu[3] = f2b(a0.w);
        pk.uu[4] = f2b(a1.x); pk.uu[5] = f2b(a1.y);
        pk.uu[6] = f2b(a1.z); pk.uu[7] = f2b(a1.w);
    } else {
        pk.v = *(const uint4*)((const u16*)x + src);
    }
    return pk.s;
}

// ---------------------------------------------------------------------------
// B-slab LDS staging.  Slab = 64 cols x 32 rows of W, stored transposed
// [col][row] with column swizzle pos(c) = ((c&7)<<3)|(c>>3):
//  - writes: thread (r=t>>3,g=t&7) scatters 8 u16 (cols g*8..+8) -> ~2-way
//  - reads:  one aligned ds_read_b128 per lane (8 contiguous rows)
// Global loads are coalesced (8 lanes = 128B contiguous row segment).
// ---------------------------------------------------------------------------
#define BPAD 40
#define POSC(c) ((((c) & 7) << 3) | ((c) >> 3))

__device__ __forceinline__ void stage_ld(u16* vals, const void* src, int f32,
                                         int ld, int row, int cb) {
    if (f32) {
        const float* sp = (const float*)src + row * ld + cb;
        float4 a0 = *(const float4*)(sp);
        float4 a1 = *(const float4*)(sp + 4);
        vals[0] = f2b(a0.x); vals[1] = f2b(a0.y);
        vals[2] = f2b(a0.z); vals[3] = f2b(a0.w);
        vals[4] = f2b(a1.x); vals[5] = f2b(a1.y);
        vals[6] = f2b(a1.z); vals[7] = f2b(a1.w);
    } else {
        union { u16 uu[8]; uint4 v; } pk;
        pk.v = *(const uint4*)((const u16*)src + row * ld + cb);
#pragma unroll
        for (int j = 0; j < 8; ++j) vals[j] = pk.uu[j];
    }
}

__device__ __forceinline__ void stage_st(u16 (*slab)[BPAD], const u16* vals,
                                         int r, int g) {
#pragma unroll
    for (int j = 0; j < 8; ++j)
        slab[POSC(g * 8 + j)][r] = vals[j];
}

__device__ __forceinline__ s16x8 ldsB(const u16 (*slab)[BPAD], int w, int lane) {
    int nn = lane & 15, kq = lane >> 4;
    int c = w * 16 + nn;
    return *(const s16x8*)&slab[POSC(c)][kq * 8];
}

// ---------------------------------------------------------------------------
// Kernel 1: QKV GEMM.  B staged via LDS (coalesced), A register-direct with
// 1-step prefetch.  isQ blocks recompute the wsuf suffix sums in LDS.
// ---------------------------------------------------------------------------
__global__ __launch_bounds__(256) void qkv_self(const void* __restrict__ x,
                                                const void* __restrict__ Wq,
                                                const void* __restrict__ Wk,
                                                const void* __restrict__ Wv,
                                                const void* __restrict__ Wpos,
                                                const void* __restrict__ rcb,
                                                const void* __restrict__ rpb,
                                                float* __restrict__ ws) {
    __shared__ alignas(16) u16 wslab[2][64][BPAD];
    __shared__ float qt[64 * 68];
    __shared__ float rpd[12];
    __shared__ float suf0[11][64];
    __shared__ float partw[3][64];
    __shared__ float wsufl[11][64];

    u16* qf = (u16*)(ws + OFF_QF);
    u16* kf = (u16*)(ws + OFF_KF);
    u16* vf = (u16*)(ws + OFF_VF);

    int tid = threadIdx.x;
    int lane = tid & 63, w = tid >> 6;
    int quad = lane >> 4, col = lane & 15;
    int ti4 = blockIdx.x;
    int tn4 = blockIdx.y;
    int tn = tn4 * 4 + w;
    int i0 = ti4 * 64;
    bool isQ = (tn4 < 8);
    int hq = tn4;

    int fx = probe_f32(x);

    // Block-level B source (64-col slab).
    const void* bsrc; int bld, c0;
    if (tn4 < 8)       { bsrc = Wq; bld = 512;  c0 = tn4 * 64; }
    else if (tn4 < 16) { bsrc = Wk; bld = 512;  c0 = (tn4 - 8) * 64; }
    else               { bsrc = Wv; bld = CDIM; c0 = (tn4 - 16) * 64; }
    int fB = probe_f32(bsrc);

    // ---- wsuf slice (isQ blocks only) ----
    s16x8 bw0, bw1;
    int f32p = 0, f32c = 0;
    if (isQ) {
        int fwp = probe_f32(Wpos);
        f32p = probe_f32(rpb);
        f32c = probe_f32(rcb);
        int d = lane;
        int base = hq * 64 + d;
        if (w == 0) {
            float s = 0.f;
            for (int f0 = 23; f0 >= 0; --f0) {
                s += ldin(Wpos, f0 * 512 + base, fwp);
                if (f0 < 11) suf0[f0][d] = s;
            }
        } else {
            float s = 0.f;
#pragma unroll 4
            for (int f0 = w * 24; f0 < w * 24 + 24; ++f0)
                s += ldin(Wpos, f0 * 512 + base, fwp);
            partw[w - 1][d] = s;
        }
        __syncthreads();
        for (int idx = tid; idx < 11 * 64; idx += 256) {
            int t = idx >> 6, dd = idx & 63;
            wsufl[t][dd] = suf0[t][dd] + partw[0][dd] + partw[1][dd] + partw[2][dd];
        }
        __syncthreads();

        int t = lane & 15, kq = lane >> 4;
        union { u16 uu[8]; s16x8 v; } p0, p1;
#pragma unroll
        for (int j = 0; j < 8; ++j) {
            float v0 = 0.f, v1 = 0.f;
            if (t < 11) {
                v0 = wsufl[t][kq * 8 + j];
                v1 = wsufl[t][32 + kq * 8 + j];
            }
            p0.uu[j] = f2b(v0); p1.uu[j] = f2b(v1);
        }
        bw0 = p0.v; bw1 = p1.v;
        if (tid < 12) {
            float s = 0.f;
            if (tid < 11) {
                for (int d2 = 0; d2 < 64; ++d2)
                    s += ldin(rpb, hq * 64 + d2, f32p) * wsufl[tid][d2];
            }
            rpd[tid] = s;
        }
    }

    f32x4 acc[4];
#pragma unroll
    for (int mt = 0; mt < 4; ++mt) acc[mt] = (f32x4){0.f, 0.f, 0.f, 0.f};

    int rs = tid >> 3, gs = tid & 7;
    u16 sv[8];
    // prologue: stage kc=0, prefetch A(kc=0)
    stage_ld(sv, bsrc, fB, bld, rs, c0 + gs * 8);
    stage_st(wslab[0], sv, rs, gs);
    s16x8 aX[4];
#pragma unroll
    for (int mt = 0; mt < 4; ++mt) aX[mt] = ldfragA(x, fx, ti4 * 4 + mt, 0, lane);
    __syncthreads();

    int buf = 0;
    for (int kc = 0; kc < 24; ++kc) {
        bool more = (kc < 23);
        if (more) stage_ld(sv, bsrc, fB, bld, (kc + 1) * 32 + rs, c0 + gs * 8);
        s16x8 bfrag = ldsB(wslab[buf], w, lane);
        s16x8 aN[4];
        if (more) {
#pragma unroll
            for (int mt = 0; mt < 4; ++mt)
                aN[mt] = ldfragA(x, fx, ti4 * 4 + mt, kc + 1, lane);
        }
#pragma unroll
        for (int mt = 0; mt < 4; ++mt)
            acc[mt] = __builtin_amdgcn_mfma_f32_16x16x32_bf16(aX[mt], bfrag, acc[mt], 0, 0, 0);
        if (more) {
            stage_st(wslab[buf ^ 1], sv, rs, gs);
#pragma unroll
            for (int mt = 0; mt < 4; ++mt) aX[mt] = aN[mt];
        }
        __syncthreads();
        buf ^= 1;
    }

    if (isQ) {
#pragma unroll
        for (int mt = 0; mt < 4; ++mt)
#pragma unroll
            for (int r = 0; r < 4; ++r)
                qt[(mt * 16 + quad * 4 + r) * 68 + w * 16 + col] = acc[mt][r] * 0.125f;
        __syncthreads();
        int m = lane & 15, kq = lane >> 4;
#pragma unroll
        for (int kc2 = 0; kc2 < 2; ++kc2) {
            union { u16 uu[8]; uint4 v; } pk;
#pragma unroll
            for (int j = 0; j < 8; ++j) {
                int d = kc2 * 32 + kq * 8 + j;
                pk.uu[j] = f2b(qt[(w * 16 + m) * 68 + d] + ldin(rcb, hq * 64 + d, f32c));
            }
            *(uint4*)(qf + (((hq * 96 + ti4 * 4 + w) * 2 + kc2) * 512) + lane * 8) = pk.v;
        }
        union { u16 uu[8]; s16x8 v; } qa0, qa1;
#pragma unroll
        for (int j = 0; j < 8; ++j) {
            qa0.uu[j] = f2b(qt[(w * 16 + m) * 68 + kq * 8 + j]);
            qa1.uu[j] = f2b(qt[(w * 16 + m) * 68 + 32 + kq * 8 + j]);
        }
        f32x4 s11a = (f32x4){0.f, 0.f, 0.f, 0.f};
        s11a = __builtin_amdgcn_mfma_f32_16x16x32_bf16(qa0.v, bw0, s11a, 0, 0, 0);
        s11a = __builtin_amdgcn_mfma_f32_16x16x32_bf16(qa1.v, bw1, s11a, 0, 0, 0);
        if (col < 12) {
            float rp = rpd[col];
            float* s11 = ws + OFF_S11;
#pragma unroll
            for (int r = 0; r < 4; ++r)
                s11[(hq * NTOK + i0 + w * 16 + quad * 4 + r) * 12 + col] = s11a[r] + rp;
        }
    } else if (tn < 64) {
        int h = (tn >> 2) - 8;
        int d = ((tn & 3) * 16) + col;
#pragma unroll
        for (int mt = 0; mt < 4; ++mt) {
            int tj = ti4 * 4 + mt;
#pragma unroll
            for (int r = 0; r < 4; ++r) {
                int nn = quad * 4 + r;
                kf[((h * 96 + tj) * 2 + (d >> 5)) * 512 + FIDX(nn, d & 31)] = f2b(acc[mt][r]);
            }
        }
    } else {
        int c = tn * 16 + col - 1024;
        int h = c / 96, d = c % 96;
        int nt = d >> 4, nn = d & 15;
#pragma unroll
        for (int mt = 0; mt < 4; ++mt) {
#pragma unroll
            for (int r = 0; r < 4; ++r) {
                int j = i0 + mt * 16 + quad * 4 + r;
                int jc = j >> 5, kk = j & 31;
                vf[((h * 48 + jc) * 6 + nt) * 512 + FIDX(nn, kk)] = f2b(acc[mt][r]);
            }
        }
    }
}

// ---------------------------------------------------------------------------
// Kernel 2: MFMA flash attention (unchanged).
// ---------------------------------------------------------------------------
__global__ __launch_bounds__(512) void attn_mfma(float* __restrict__ ws) {
    __shared__ float s11b[192];
    __shared__ alignas(16) u16 pbuf[8][16 * 36];
    __shared__ float Om[8][16 * 96];
    __shared__ float lw[8][16];

    const u16* qf = (const u16*)(ws + OFF_QF);
    const u16* kf = (const u16*)(ws + OFF_KF);
    const u16* vf = (const u16*)(ws + OFF_VF);
    const float* s11 = ws + OFF_S11;
    u16* aof = (u16*)(ws + OFF_AOF);

    int h = blockIdx.x & 7;               // XCD-affine
    int ti = blockIdx.x >> 3;
    int i0 = ti * 16;
    int tid = threadIdx.x;
    int wv = tid >> 6, lane = tid & 63;
    int quad = lane >> 4, col = lane & 15;

    if (tid < 192) s11b[tid] = s11[(h * NTOK + i0 + tid / 12) * 12 + tid % 12];
    const u16* qp = qf + ((h * 96 + ti) * 2) * 512 + lane * 8;
    s16x8 a_lo = *(const s16x8*)(qp);
    s16x8 a_hi = *(const s16x8*)(qp + 512);
    __syncthreads();

    f32x4 O[6];
    float lsum[4];
#pragma unroll
    for (int nt = 0; nt < 6; ++nt) O[nt] = (f32x4){0.f, 0.f, 0.f, 0.f};
#pragma unroll
    for (int r = 0; r < 4; ++r) lsum[r] = 0.f;

    const u16* kbase = kf + ((h * 96 + wv * 12) * 2) * 512 + lane * 8;
    s16x8 k0lo = *(const s16x8*)(kbase);
    s16x8 k0hi = *(const s16x8*)(kbase + 512);
    s16x8 k1lo = *(const s16x8*)(kbase + 1024);
    s16x8 k1hi = *(const s16x8*)(kbase + 1536);

    for (int c = 0; c < 6; ++c) {
        f32x4 t0 = (f32x4){0.f, 0.f, 0.f, 0.f};
        f32x4 t1 = (f32x4){0.f, 0.f, 0.f, 0.f};
        t0 = __builtin_amdgcn_mfma_f32_16x16x32_bf16(a_lo, k0lo, t0, 0, 0, 0);
        t0 = __builtin_amdgcn_mfma_f32_16x16x32_bf16(a_hi, k0hi, t0, 0, 0, 0);
        t1 = __builtin_amdgcn_mfma_f32_16x16x32_bf16(a_lo, k1lo, t1, 0, 0, 0);
        t1 = __builtin_amdgcn_mfma_f32_16x16x32_bf16(a_hi, k1hi, t1, 0, 0, 0);
        if (c < 5) {
            const u16* kn = kbase + (c + 1) * 2048;
            k0lo = *(const s16x8*)(kn);
            k0hi = *(const s16x8*)(kn + 512);
            k1lo = *(const s16x8*)(kn + 1024);
            k1hi = *(const s16x8*)(kn + 1536);
        }
        int j0 = wv * 192 + c * 32;
        int lo1 = j0 - (i0 + 15), lo2 = i0 - (j0 + 31);
        int dmin = lo1 > 0 ? lo1 : (lo2 > 0 ? lo2 : 0);
        int dm1 = i0 + 15 - j0, dm2 = j0 + 31 - i0;
        int dmax = dm1 > dm2 ? dm1 : dm2;
        int tlo = 31 - __builtin_clz(dmin + 1);
        int thi = 31 - __builtin_clz(dmax + 1);
        if (tlo == thi) {
#pragma unroll
            for (int r = 0; r < 4; ++r) {
                int row = quad * 4 + r;
                float bv = s11b[row * 12 + tlo] - 12.f;
                float p0 = __expf(t0[r] + bv);
                float p1 = __expf(t1[r] + bv);
                pbuf[wv][row * 36 + col] = f2b(p0);
                pbuf[wv][row * 36 + 16 + col] = f2b(p1);
                lsum[r] += p0 + p1;
            }
        } else {
#pragma unroll
            for (int r = 0; r < 4; ++r) {
                int row = quad * 4 + r;
                int ig = i0 + row;
                int d0 = ig - (j0 + col); d0 = d0 < 0 ? -d0 : d0;
                int d1 = ig - (j0 + 16 + col); d1 = d1 < 0 ? -d1 : d1;
                float v0 = t0[r] + s11b[row * 12 + (31 - __builtin_clz(d0 + 1))];
                float v1 = t1[r] + s11b[row * 12 + (31 - __builtin_clz(d1 + 1))];
                float p0 = __expf(v0 - 12.f);
                float p1 = __expf(v1 - 12.f);
                pbuf[wv][row * 36 + col] = f2b(p0);
                pbuf[wv][row * 36 + 16 + col] = f2b(p1);
                lsum[r] += p0 + p1;
            }
        }
        int jc = wv * 6 + c;
        const u16* pr = &pbuf[wv][col * 36 + quad * 8];
        union { s16x8 v; uint2 u2[2]; } pa;
        pa.u2[0] = *(const uint2*)(pr);
        pa.u2[1] = *(const uint2*)(pr + 4);
        const u16* vp = vf + ((h * 48 + jc) * 6) * 512 + lane * 8;
#pragma unroll
        for (int nt = 0; nt < 6; ++nt) {
            s16x8 vfr = *(const s16x8*)(vp + nt * 512);
            O[nt] = __builtin_amdgcn_mfma_f32_16x16x32_bf16(pa.v, vfr, O[nt], 0, 0, 0);
        }
    }

#pragma unroll
    for (int off = 1; off < 16; off <<= 1)
#pragma unroll
        for (int r = 0; r < 4; ++r) lsum[r] += __shfl_xor(lsum[r], off);
    if (col == 0)
#pragma unroll
        for (int r = 0; r < 4; ++r) lw[wv][quad * 4 + r] = lsum[r];
#pragma unroll
    for (int r = 0; r < 4; ++r) {
        int row = quad * 4 + r;
#pragma unroll
        for (int nt = 0; nt < 6; ++nt)
            Om[wv][row * 96 + nt * 16 + col] = O[nt][r];
    }
    __syncthreads();
    for (int idx = tid; idx < 16 * 96; idx += 512) {
        int row = idx / 96, cc = idx % 96;
        float L = 0.f, val = 0.f;
#pragma unroll
        for (int v = 0; v < 8; ++v) { L += lw[v][row]; val += Om[v][idx]; }
        aof[(ti * 24 + h * 3 + (cc >> 5)) * 512 + FIDX(row, cc & 31)] = f2b(val / L);
    }
}

// ---------------------------------------------------------------------------
// Kernel 3: output GEMM.  Wout staged via LDS (coalesced), A frag-major with
// 1-step prefetch.
// ---------------------------------------------------------------------------
__global__ __launch_bounds__(256) void out_self(const void* __restrict__ bout,
                                                const void* __restrict__ Wout,
                                                float* __restrict__ ws,
                                                float* __restrict__ out) {
    __shared__ alignas(16) u16 wslab[2][64][BPAD];
    const u16* af = (const u16*)(ws + OFF_AOF);
    int f32b = probe_f32(bout);
    int fW = probe_f32(Wout);

    int tid = threadIdx.x;
    int lane = tid & 63, w = tid >> 6;
    int quad = lane >> 4, col = lane & 15;
    int ti4 = blockIdx.x;
    int i0 = ti4 * 64;
    int n0 = blockIdx.y * 64;

    f32x4 acc[4];
#pragma unroll
    for (int mt = 0; mt < 4; ++mt) acc[mt] = (f32x4){0.f, 0.f, 0.f, 0.f};

    const u16* ap = af + (ti4 * 4 * 24) * 512 + lane * 8;
    int rs = tid >> 3, gs = tid & 7;
    u16 sv[8];
    stage_ld(sv, Wout, fW, CDIM, rs, n0 + gs * 8);
    stage_st(wslab[0], sv, rs, gs);
    s16x8 aX[4];
#pragma unroll
    for (int mt = 0; mt < 4; ++mt) aX[mt] = *(const s16x8*)(ap + (mt * 24) * 512);
    __syncthreads();

    int buf = 0;
    for (int kc = 0; kc < 24; ++kc) {
        bool more = (kc < 23);
        if (more) stage_ld(sv, Wout, fW, CDIM, (kc + 1) * 32 + rs, n0 + gs * 8);
        s16x8 bfrag = ldsB(wslab[buf], w, lane);
        s16x8 aN[4];
        if (more) {
#pragma unroll
            for (int mt = 0; mt < 4; ++mt)
                aN[mt] = *(const s16x8*)(ap + (mt * 24 + kc + 1) * 512);
        }
#pragma unroll
        for (int mt = 0; mt < 4; ++mt)
            acc[mt] = __builtin_amdgcn_mfma_f32_16x16x32_bf16(aX[mt], bfrag, acc[mt], 0, 0, 0);
        if (more) {
            stage_st(wslab[buf ^ 1], sv, rs, gs);
#pragma unroll
            for (int mt = 0; mt < 4; ++mt) aX[mt] = aN[mt];
        }
        __syncthreads();
        buf ^= 1;
    }

    int c = n0 + w * 16 + col;
    float bias = ldin(bout, c, f32b);
#pragma unroll
    for (int mt = 0; mt < 4; ++mt) {
#pragma unroll
        for (int r = 0; r < 4; ++r) {
            int i = i0 + mt * 16 + quad * 4 + r;
            out[i * CDIM + c] = acc[mt][r] + bias;
        }
    }
}

// ---------------------------------------------------------------------------
extern "C" void kernel_launch(void* const* d_in, const int* in_sizes, int n_in,
                              void* d_out, int out_size, void* d_ws, size_t ws_size,
                              hipStream_t stream) {
    float* out = (float*)d_out;
    float* ws = (float*)d_ws;

    const int want[9] = {1179648, 393216, 393216, 589824, 589824, 768, 49152, 512, 512};
    int role2in[9], used[9] = {0};
    bool ok = (n_in == 9);
    if (ok) {
        for (int r = 0; r < 9; ++r) {
            int found = -1;
            for (int i = 0; i < 9 && found < 0; ++i)
                if (!used[i] && in_sizes[i] == want[r]) found = i;
            if (found < 0) { ok = false; break; }
            used[found] = 1;
            role2in[r] = found;
        }
    }
    if (!ok) for (int r = 0; r < 9; ++r) role2in[r] = r;

    const void* x    = d_in[role2in[0]];
    const void* Wq   = d_in[role2in[1]];
    const void* Wk   = d_in[role2in[2]];
    const void* Wv   = d_in[role2in[3]];
    const void* Wout = d_in[role2in[4]];
    const void* bout = d_in[role2in[5]];
    const void* Wpos = d_in[role2in[6]];
    const void* rcb  = d_in[role2in[7]];
    const void* rpb  = d_in[role2in[8]];

    hipLaunchKernelGGL(qkv_self, dim3(24, 28), dim3(256), 0, stream,
                       x, Wq, Wk, Wv, Wpos, rcb, rpb, ws);
    hipLaunchKernelGGL(attn_mfma, dim3(768), dim3(512), 0, stream, ws);
    hipLaunchKernelGGL(out_self, dim3(24, 12), dim3(256), 0, stream,
                       bout, Wout, ws, out);
}

// Round 4
// 161.308 us; speedup vs baseline: 1.1720x; 1.1720x over previous
//
#include <hip/hip_runtime.h>
#include <stdint.h>

#define NTOK 1536
#define CDIM 768
#define NH 8
#define DKH 64
#define DVH 96
#define NF 96

typedef unsigned short u16;
typedef __attribute__((ext_vector_type(8))) short s16x8;   // 8 bf16 (4 VGPRs)
typedef __attribute__((ext_vector_type(4))) float f32x4;   // MFMA acc

__device__ __forceinline__ float b2f(u16 u) {
    union { uint32_t i; float f; } v; v.i = ((uint32_t)u) << 16; return v.f;
}
__device__ __forceinline__ u16 f2b(float f) {
    union { float f; uint32_t i; } v; v.f = f;
    uint32_t x = v.i;
    return (u16)((x + 0x7FFFu + ((x >> 16) & 1u)) >> 16);
}
__device__ __forceinline__ float ldin(const void* p, int i, int f32) {
    return f32 ? ((const float*)p)[i] : b2f(((const u16*)p)[i]);
}

// Inline wave-uniform dtype probe: scans first 256 u16 words.  A true-bf16
// buffer never decodes |v|>=1e6; fp32 mantissa-low words do w.p. ~0.42 each
// (~128 of the 256 samples) -> miss prob ~3e-29.  Returns 1 iff fp32.
__device__ __forceinline__ int probe_f32(const void* p) {
    const u16* a = (const u16*)p;
    int lane = threadIdx.x & 63;
    int bad = 0;
#pragma unroll
    for (int t = 0; t < 4; ++t) {
        float v = b2f(a[lane + t * 64]);
        if (!(fabsf(v) < 1e6f)) bad = 1;
    }
    return __ballot(bad) != 0ull;
}

// Fragment-major: element (m, kk) of a (16 x 32k) 512-elem block sits at
// ((kk>>3)*16 + m)*8 + (kk&7)  == lane*8 + slot.
#define FIDX(m, kk) ((((kk) >> 3) * 16 + (m)) * 8 + ((kk) & 7))

// ---------------------------------------------------------------------------
// ws layout (float offsets). ~14.8 MB.
// ---------------------------------------------------------------------------
#define OFF_WSUF 16
#define OFF_S11  (OFF_WSUF + 5632)
#define OFF_QF   (OFF_S11 + 147456)     // u16: qfrag  (h,ti:96,kc2:2)  A-frags
#define OFF_KF   (OFF_QF + 393216)      // u16: kfrag  (h,tj:96,kc2:2)  B-frags
#define OFF_VF   (OFF_KF + 393216)      // u16: vfrag  (h,jc:48,nt:6)   B-frags
#define OFF_AOF  (OFF_VF + 589824)      // u16: aofrag (ti:96,kc:24)    A-frags
#define OFF_XF   (OFF_AOF + 589824)     // u16: xfrag  (ti:96,kc:24)    A-frags
#define OFF_WF   (OFF_XF + 589824)      // u16: wfrag  (tn:112,kc:24)   B-frags
#define OFF_WOF  (OFF_WF + 688128)      // u16: wofrag (tn:48,kc:24)    B-frags

// ---------------------------------------------------------------------------
// Kernel PR: build fragment buffers.  NO LDS, NO barriers, high MLP.
// ---------------------------------------------------------------------------
__global__ __launch_bounds__(256) void prep(const void* __restrict__ x,
                                            const void* __restrict__ Wq,
                                            const void* __restrict__ Wk,
                                            const void* __restrict__ Wv,
                                            const void* __restrict__ Wout,
                                            const void* __restrict__ Wpos,
                                            float* __restrict__ ws) {
    int bx = blockIdx.x, tid = threadIdx.x;
    int wv = tid >> 6, L = tid & 63;

    if (bx < 144) {
        int f = probe_f32(x);
        u16* dst = (u16*)(ws + OFF_XF);
        int cbase = (bx * 4 + wv) * 4;
        int m = L & 15, kq = L >> 4;
        int srcs[4];
#pragma unroll
        for (int c = 0; c < 4; ++c) {
            int ch = cbase + c;
            int ti = ch / 24, kc = ch % 24;
            srcs[c] = (ti * 16 + m) * CDIM + kc * 32 + kq * 8;
        }
        if (f) {
            float4 a[4][2];
#pragma unroll
            for (int c = 0; c < 4; ++c) {
                const float* xp = (const float*)x + srcs[c];
                a[c][0] = *(const float4*)(xp);
                a[c][1] = *(const float4*)(xp + 4);
            }
#pragma unroll
            for (int c = 0; c < 4; ++c) {
                union { u16 u[8]; uint4 v; } pk;
                pk.u[0] = f2b(a[c][0].x); pk.u[1] = f2b(a[c][0].y);
                pk.u[2] = f2b(a[c][0].z); pk.u[3] = f2b(a[c][0].w);
                pk.u[4] = f2b(a[c][1].x); pk.u[5] = f2b(a[c][1].y);
                pk.u[6] = f2b(a[c][1].z); pk.u[7] = f2b(a[c][1].w);
                *(uint4*)(dst + (cbase + c) * 512 + L * 8) = pk.v;
            }
        } else {
            uint4 v[4];
#pragma unroll
            for (int c = 0; c < 4; ++c) v[c] = *(const uint4*)((const u16*)x + srcs[c]);
#pragma unroll
            for (int c = 0; c < 4; ++c)
                *(uint4*)(dst + (cbase + c) * 512 + L * 8) = v[c];
        }
        return;
    }
    if (bx < 1104) {
        int c = (bx - 144) * 4 + wv;
        const void* src; int ld, cn0; u16* dst; int kc;
        if (c < 2688) {
            int tn = c / 24; kc = c % 24;
            int n0 = tn * 16;
            dst = (u16*)(ws + OFF_WF) + c * 512;
            if (n0 < 512)       { src = Wq; ld = 512;  cn0 = n0; }
            else if (n0 < 1024) { src = Wk; ld = 512;  cn0 = n0 - 512; }
            else                { src = Wv; ld = CDIM; cn0 = n0 - 1024; }
        } else {
            int c2 = c - 2688;
            int tn = c2 / 24; kc = c2 % 24;
            dst = (u16*)(ws + OFF_WOF) + c2 * 512;
            src = Wout; ld = CDIM; cn0 = tn * 16;
        }
        int f = probe_f32(src);
        int nn = L & 15, kq = L >> 4;
        int base = (kc * 32 + kq * 8) * ld + cn0 + nn;
        union { u16 u[8]; uint4 v; } pk;
        if (f) {
            const float* sp = (const float*)src + base;
            float a0 = sp[0], a1 = sp[ld], a2 = sp[2 * ld], a3 = sp[3 * ld];
            float a4 = sp[4 * ld], a5 = sp[5 * ld], a6 = sp[6 * ld], a7 = sp[7 * ld];
            pk.u[0] = f2b(a0); pk.u[1] = f2b(a1); pk.u[2] = f2b(a2); pk.u[3] = f2b(a3);
            pk.u[4] = f2b(a4); pk.u[5] = f2b(a5); pk.u[6] = f2b(a6); pk.u[7] = f2b(a7);
        } else {
            const u16* sp = (const u16*)src + base;
            pk.u[0] = sp[0]; pk.u[1] = sp[ld]; pk.u[2] = sp[2 * ld]; pk.u[3] = sp[3 * ld];
            pk.u[4] = sp[4 * ld]; pk.u[5] = sp[5 * ld]; pk.u[6] = sp[6 * ld]; pk.u[7] = sp[7 * ld];
        }
        *(uint4*)(dst + L * 8) = pk.v;
        return;
    }
    // ---- wsuf ----
    int t = bx - 1104;
    int f = probe_f32(Wpos);
    for (int hd = tid; hd < 512; hd += 256) {
        float s0 = 0.f, s1 = 0.f, s2 = 0.f, s3 = 0.f;
        int f0 = t;
        for (; f0 + 4 <= NF; f0 += 4) {
            s0 += ldin(Wpos, f0 * 512 + hd, f);
            s1 += ldin(Wpos, (f0 + 1) * 512 + hd, f);
            s2 += ldin(Wpos, (f0 + 2) * 512 + hd, f);
            s3 += ldin(Wpos, (f0 + 3) * 512 + hd, f);
        }
        for (; f0 < NF; ++f0) s0 += ldin(Wpos, f0 * 512 + hd, f);
        ws[OFF_WSUF + t * 512 + hd] = (s0 + s1) + (s2 + s3);
    }
}

// ---------------------------------------------------------------------------
// Kernel 1: QKV GEMM, register-direct MFMA (proven R0 version).
// ---------------------------------------------------------------------------
__global__ __launch_bounds__(256) void qkv_reg(const void* __restrict__ rcb,
                                               const void* __restrict__ rpb,
                                               float* __restrict__ ws) {
    __shared__ float qt[64 * 68];
    __shared__ float rpd[12];
    const u16* xf = (const u16*)(ws + OFF_XF);
    const u16* wf = (const u16*)(ws + OFF_WF);
    u16* qf = (u16*)(ws + OFF_QF);
    u16* kf = (u16*)(ws + OFF_KF);
    u16* vf = (u16*)(ws + OFF_VF);

    int tid = threadIdx.x;
    int lane = tid & 63, w = tid >> 6;
    int quad = lane >> 4, col = lane & 15;
    int ti4 = blockIdx.x;
    int tn4 = blockIdx.y;
    int tn = tn4 * 4 + w;
    int i0 = ti4 * 64;
    bool isQ = (tn4 < 8);
    int hq = tn4;

    s16x8 bw0, bw1;
    int f32p = 0, f32c = 0;
    if (isQ) {
        f32p = probe_f32(rpb);
        f32c = probe_f32(rcb);
        int t = lane & 15, kq = lane >> 4;
        union { u16 u[8]; s16x8 v; } p0, p1;
#pragma unroll
        for (int j = 0; j < 8; ++j) {
            float v0 = 0.f, v1 = 0.f;
            if (t < 11) {
                v0 = ws[OFF_WSUF + t * 512 + hq * 64 + kq * 8 + j];
                v1 = ws[OFF_WSUF + t * 512 + hq * 64 + 32 + kq * 8 + j];
            }
            p0.u[j] = f2b(v0); p1.u[j] = f2b(v1);
        }
        bw0 = p0.v; bw1 = p1.v;
        if (tid < 12) {
            float s = 0.f;
            if (tid < 11) {
                const float* wp = ws + OFF_WSUF + tid * 512 + hq * 64;
                for (int d = 0; d < 64; ++d) s += ldin(rpb, hq * 64 + d, f32p) * wp[d];
            }
            rpd[tid] = s;
        }
    }

    f32x4 acc[4];
#pragma unroll
    for (int mt = 0; mt < 4; ++mt) acc[mt] = (f32x4){0.f, 0.f, 0.f, 0.f};

    const u16* bp = wf + (tn * 24) * 512 + lane * 8;
    const u16* ap = xf + (ti4 * 4 * 24) * 512 + lane * 8;
#pragma unroll 4
    for (int kc = 0; kc < 24; ++kc) {
        s16x8 bfrag = *(const s16x8*)(bp + kc * 512);
#pragma unroll
        for (int mt = 0; mt < 4; ++mt) {
            s16x8 afrag = *(const s16x8*)(ap + (mt * 24 + kc) * 512);
            acc[mt] = __builtin_amdgcn_mfma_f32_16x16x32_bf16(afrag, bfrag, acc[mt], 0, 0, 0);
        }
    }

    if (isQ) {
#pragma unroll
        for (int mt = 0; mt < 4; ++mt)
#pragma unroll
            for (int r = 0; r < 4; ++r)
                qt[(mt * 16 + quad * 4 + r) * 68 + w * 16 + col] = acc[mt][r] * 0.125f;
        __syncthreads();
        int m = lane & 15, kq = lane >> 4;
#pragma unroll
        for (int kc2 = 0; kc2 < 2; ++kc2) {
            union { u16 u[8]; uint4 v; } pk;
#pragma unroll
            for (int j = 0; j < 8; ++j) {
                int d = kc2 * 32 + kq * 8 + j;
                pk.u[j] = f2b(qt[(w * 16 + m) * 68 + d] + ldin(rcb, hq * 64 + d, f32c));
            }
            *(uint4*)(qf + (((hq * 96 + ti4 * 4 + w) * 2 + kc2) * 512) + lane * 8) = pk.v;
        }
        union { u16 u[8]; s16x8 v; } qa0, qa1;
#pragma unroll
        for (int j = 0; j < 8; ++j) {
            qa0.u[j] = f2b(qt[(w * 16 + m) * 68 + kq * 8 + j]);
            qa1.u[j] = f2b(qt[(w * 16 + m) * 68 + 32 + kq * 8 + j]);
        }
        f32x4 s11a = (f32x4){0.f, 0.f, 0.f, 0.f};
        s11a = __builtin_amdgcn_mfma_f32_16x16x32_bf16(qa0.v, bw0, s11a, 0, 0, 0);
        s11a = __builtin_amdgcn_mfma_f32_16x16x32_bf16(qa1.v, bw1, s11a, 0, 0, 0);
        if (col < 12) {
            float rp = rpd[col];
            float* s11 = ws + OFF_S11;
#pragma unroll
            for (int r = 0; r < 4; ++r)
                s11[(hq * NTOK + i0 + w * 16 + quad * 4 + r) * 12 + col] = s11a[r] + rp;
        }
    } else if (tn < 64) {
        int h = (tn >> 2) - 8;
        int d = ((tn & 3) * 16) + col;
#pragma unroll
        for (int mt = 0; mt < 4; ++mt) {
            int tj = ti4 * 4 + mt;
#pragma unroll
            for (int r = 0; r < 4; ++r) {
                int nn = quad * 4 + r;
                kf[((h * 96 + tj) * 2 + (d >> 5)) * 512 + FIDX(nn, d & 31)] = f2b(acc[mt][r]);
            }
        }
    } else {
        int c = tn * 16 + col - 1024;
        int h = c / 96, d = c % 96;
        int nt = d >> 4, nn = d & 15;
#pragma unroll
        for (int mt = 0; mt < 4; ++mt) {
#pragma unroll
            for (int r = 0; r < 4; ++r) {
                int j = i0 + mt * 16 + quad * 4 + r;
                int jc = j >> 5, kk = j & 31;
                vf[((h * 48 + jc) * 6 + nt) * 512 + FIDX(nn, kk)] = f2b(acc[mt][r]);
            }
        }
    }
}

// ---------------------------------------------------------------------------
// Kernel 3: MFMA flash attention.  CHANGES vs R0 (the 147us baseline):
//  - Om reduced 8 waves -> 4 LDS slots (2-stage reduction): LDS 62KB -> ~35KB
//  - __launch_bounds__(512, 6): cap VGPR<=85 so 3 blocks/CU materialize
//  => all 768 blocks resident in ONE scheduling round, 24 waves/CU.
// ---------------------------------------------------------------------------
__global__ __launch_bounds__(512, 6) void attn_mfma(float* __restrict__ ws) {
    __shared__ float s11b[192];
    __shared__ alignas(16) u16 pbuf[8][16 * 36];
    __shared__ float Om4[4][16 * 96];
    __shared__ float lw[8][16];

    const u16* qf = (const u16*)(ws + OFF_QF);
    const u16* kf = (const u16*)(ws + OFF_KF);
    const u16* vf = (const u16*)(ws + OFF_VF);
    const float* s11 = ws + OFF_S11;
    u16* aof = (u16*)(ws + OFF_AOF);

    int h = blockIdx.x & 7;               // XCD-affine
    int ti = blockIdx.x >> 3;
    int i0 = ti * 16;
    int tid = threadIdx.x;
    int wv = tid >> 6, lane = tid & 63;
    int quad = lane >> 4, col = lane & 15;

    if (tid < 192) s11b[tid] = s11[(h * NTOK + i0 + tid / 12) * 12 + tid % 12];
    const u16* qp = qf + ((h * 96 + ti) * 2) * 512 + lane * 8;
    s16x8 a_lo = *(const s16x8*)(qp);
    s16x8 a_hi = *(const s16x8*)(qp + 512);
    __syncthreads();

    f32x4 O[6];
    float lsum[4];
#pragma unroll
    for (int nt = 0; nt < 6; ++nt) O[nt] = (f32x4){0.f, 0.f, 0.f, 0.f};
#pragma unroll
    for (int r = 0; r < 4; ++r) lsum[r] = 0.f;

    // prefetch chunk 0 K-frags
    const u16* kbase = kf + ((h * 96 + wv * 12) * 2) * 512 + lane * 8;
    s16x8 k0lo = *(const s16x8*)(kbase);
    s16x8 k0hi = *(const s16x8*)(kbase + 512);
    s16x8 k1lo = *(const s16x8*)(kbase + 1024);
    s16x8 k1hi = *(const s16x8*)(kbase + 1536);

    for (int c = 0; c < 6; ++c) {
        // ---- QK^T with current K regs ----
        f32x4 t0 = (f32x4){0.f, 0.f, 0.f, 0.f};
        f32x4 t1 = (f32x4){0.f, 0.f, 0.f, 0.f};
        t0 = __builtin_amdgcn_mfma_f32_16x16x32_bf16(a_lo, k0lo, t0, 0, 0, 0);
        t0 = __builtin_amdgcn_mfma_f32_16x16x32_bf16(a_hi, k0hi, t0, 0, 0, 0);
        t1 = __builtin_amdgcn_mfma_f32_16x16x32_bf16(a_lo, k1lo, t1, 0, 0, 0);
        t1 = __builtin_amdgcn_mfma_f32_16x16x32_bf16(a_hi, k1hi, t1, 0, 0, 0);
        // ---- prefetch next chunk's K frags ----
        if (c < 5) {
            const u16* kn = kbase + (c + 1) * 2048;
            k0lo = *(const s16x8*)(kn);
            k0hi = *(const s16x8*)(kn + 512);
            k1lo = *(const s16x8*)(kn + 1024);
            k1hi = *(const s16x8*)(kn + 1536);
        }
        // ---- bias + exp(s-12) + store P ----
        int j0 = wv * 192 + c * 32;
        int lo1 = j0 - (i0 + 15), lo2 = i0 - (j0 + 31);
        int dmin = lo1 > 0 ? lo1 : (lo2 > 0 ? lo2 : 0);
        int dm1 = i0 + 15 - j0, dm2 = j0 + 31 - i0;
        int dmax = dm1 > dm2 ? dm1 : dm2;
        int tlo = 31 - __builtin_clz(dmin + 1);
        int thi = 31 - __builtin_clz(dmax + 1);
        if (tlo == thi) {
#pragma unroll
            for (int r = 0; r < 4; ++r) {
                int row = quad * 4 + r;
                float bv = s11b[row * 12 + tlo] - 12.f;
                float p0 = __expf(t0[r] + bv);
                float p1 = __expf(t1[r] + bv);
                pbuf[wv][row * 36 + col] = f2b(p0);
                pbuf[wv][row * 36 + 16 + col] = f2b(p1);
                lsum[r] += p0 + p1;
            }
        } else {
#pragma unroll
            for (int r = 0; r < 4; ++r) {
                int row = quad * 4 + r;
                int ig = i0 + row;
                int d0 = ig - (j0 + col); d0 = d0 < 0 ? -d0 : d0;
                int d1 = ig - (j0 + 16 + col); d1 = d1 < 0 ? -d1 : d1;
                float v0 = t0[r] + s11b[row * 12 + (31 - __builtin_clz(d0 + 1))];
                float v1 = t1[r] + s11b[row * 12 + (31 - __builtin_clz(d1 + 1))];
                float p0 = __expf(v0 - 12.f);
                float p1 = __expf(v1 - 12.f);
                pbuf[wv][row * 36 + col] = f2b(p0);
                pbuf[wv][row * 36 + 16 + col] = f2b(p1);
                lsum[r] += p0 + p1;
            }
        }
        // ---- PV ----
        int jc = wv * 6 + c;
        const u16* pr = &pbuf[wv][col * 36 + quad * 8];
        union { s16x8 v; uint2 u2[2]; } pa;
        pa.u2[0] = *(const uint2*)(pr);
        pa.u2[1] = *(const uint2*)(pr + 4);
        const u16* vp = vf + ((h * 48 + jc) * 6) * 512 + lane * 8;
#pragma unroll
        for (int nt = 0; nt < 6; ++nt) {
            s16x8 vfr = *(const s16x8*)(vp + nt * 512);
            O[nt] = __builtin_amdgcn_mfma_f32_16x16x32_bf16(pa.v, vfr, O[nt], 0, 0, 0);
        }
    }

#pragma unroll
    for (int off = 1; off < 16; off <<= 1)
#pragma unroll
        for (int r = 0; r < 4; ++r) lsum[r] += __shfl_xor(lsum[r], off);
    if (col == 0)
#pragma unroll
        for (int r = 0; r < 4; ++r) lw[wv][quad * 4 + r] = lsum[r];
    // ---- 2-stage cross-wave O reduction (8 waves -> 4 LDS slots) ----
    if (wv >= 4) {
#pragma unroll
        for (int r = 0; r < 4; ++r) {
            int row = quad * 4 + r;
#pragma unroll
            for (int nt = 0; nt < 6; ++nt)
                Om4[wv - 4][row * 96 + nt * 16 + col] = O[nt][r];
        }
    }
    __syncthreads();
    if (wv < 4) {
#pragma unroll
        for (int r = 0; r < 4; ++r) {
            int row = quad * 4 + r;
#pragma unroll
            for (int nt = 0; nt < 6; ++nt)
                Om4[wv][row * 96 + nt * 16 + col] += O[nt][r];
        }
    }
    __syncthreads();
    for (int idx = tid; idx < 16 * 96; idx += 512) {
        int row = idx / 96, cc = idx % 96;
        float L = 0.f, val = 0.f;
#pragma unroll
        for (int v = 0; v < 8; ++v) L += lw[v][row];
#pragma unroll
        for (int v = 0; v < 4; ++v) val += Om4[v][idx];
        aof[(ti * 24 + h * 3 + (cc >> 5)) * 512 + FIDX(row, cc & 31)] = f2b(val / L);
    }
}

// ---------------------------------------------------------------------------
// Kernel 4: output GEMM, register-direct MFMA (proven R0 version).
// ---------------------------------------------------------------------------
__global__ __launch_bounds__(256) void out_reg(const void* __restrict__ bout,
                                               float* __restrict__ ws,
                                               float* __restrict__ out) {
    const u16* af = (const u16*)(ws + OFF_AOF);
    const u16* wof = (const u16*)(ws + OFF_WOF);
    int f32b = probe_f32(bout);

    int tid = threadIdx.x;
    int lane = tid & 63, w = tid >> 6;
    int quad = lane >> 4, col = lane & 15;
    int ti4 = blockIdx.x;
    int tn = blockIdx.y * 4 + w;
    int i0 = ti4 * 64;
    int n0 = blockIdx.y * 64;

    f32x4 acc[4];
#pragma unroll
    for (int mt = 0; mt < 4; ++mt) acc[mt] = (f32x4){0.f, 0.f, 0.f, 0.f};

    const u16* bp = wof + (tn * 24) * 512 + lane * 8;
    const u16* ap = af + (ti4 * 4 * 24) * 512 + lane * 8;
#pragma unroll 4
    for (int kc = 0; kc < 24; ++kc) {
        s16x8 bfrag = *(const s16x8*)(bp + kc * 512);
#pragma unroll
        for (int mt = 0; mt < 4; ++mt) {
            s16x8 afrag = *(const s16x8*)(ap + (mt * 24 + kc) * 512);
            acc[mt] = __builtin_amdgcn_mfma_f32_16x16x32_bf16(afrag, bfrag, acc[mt], 0, 0, 0);
        }
    }

    int c = n0 + w * 16 + col;
    float bias = ldin(bout, c, f32b);
#pragma unroll
    for (int mt = 0; mt < 4; ++mt) {
#pragma unroll
        for (int r = 0; r < 4; ++r) {
            int i = i0 + mt * 16 + quad * 4 + r;
            out[i * CDIM + c] = acc[mt][r] + bias;
        }
    }
}

// ---------------------------------------------------------------------------
extern "C" void kernel_launch(void* const* d_in, const int* in_sizes, int n_in,
                              void* d_out, int out_size, void* d_ws, size_t ws_size,
                              hipStream_t stream) {
    float* out = (float*)d_out;
    float* ws = (float*)d_ws;

    const int want[9] = {1179648, 393216, 393216, 589824, 589824, 768, 49152, 512, 512};
    int role2in[9], used[9] = {0};
    bool ok = (n_in == 9);
    if (ok) {
        for (int r = 0; r < 9; ++r) {
            int found = -1;
            for (int i = 0; i < 9 && found < 0; ++i)
                if (!used[i] && in_sizes[i] == want[r]) found = i;
            if (found < 0) { ok = false; break; }
            used[found] = 1;
            role2in[r] = found;
        }
    }
    if (!ok) for (int r = 0; r < 9; ++r) role2in[r] = r;

    const void* x    = d_in[role2in[0]];
    const void* Wq   = d_in[role2in[1]];
    const void* Wk   = d_in[role2in[2]];
    const void* Wv   = d_in[role2in[3]];
    const void* Wout = d_in[role2in[4]];
    const void* bout = d_in[role2in[5]];
    const void* Wpos = d_in[role2in[6]];
    const void* rcb  = d_in[role2in[7]];
    const void* rpb  = d_in[role2in[8]];

    hipLaunchKernelGGL(prep, dim3(1115), dim3(256), 0, stream,
                       x, Wq, Wk, Wv, Wout, Wpos, ws);
    hipLaunchKernelGGL(qkv_reg, dim3(24, 28), dim3(256), 0, stream,
                       rcb, rpb, ws);
    hipLaunchKernelGGL(attn_mfma, dim3(768), dim3(512), 0, stream, ws);
    hipLaunchKernelGGL(out_reg, dim3(24, 12), dim3(256), 0, stream,
                       bout, ws, out);
}